// Round 1
// baseline (1441.811 us; speedup 1.0000x reference)
//
#include <hip/hip_runtime.h>
#include <math.h>

#define NN 100000
#define DIM 64
#define ENT_OFFSET 20000

// ---------------- Stage A: holographic fusion ----------------
// one 64-lane wave per node, 4 nodes per 256-thread block
__global__ void fuse_kernel(const float* __restrict__ aux,      // [N,3]
                            const float* __restrict__ entity,   // [N,64]
                            const float* __restrict__ type_emb, // [2,64]
                            const float* __restrict__ W_aux,    // [64,3]
                            const float* __restrict__ b_aux,    // [64]
                            float* __restrict__ all_e)          // [N,160], write cols 0..63
{
    int n    = blockIdx.x * 4 + (threadIdx.x >> 6);
    int lane = threadIdx.x & 63;

    float a0 = log1pf(aux[n * 3 + 0]);
    float a1 = log1pf(aux[n * 3 + 1]);
    float a2 = log1pf(aux[n * 3 + 2]);
    float g  = a0 * W_aux[lane * 3 + 0] + a1 * W_aux[lane * 3 + 1]
             + a2 * W_aux[lane * 3 + 2] + b_aux[lane];
    g = 1.0f / (1.0f + expf(-g)) * 0.15f + 1.0f;

    float v  = entity[n * 64 + lane] * g;
    float ss = v * v;
    #pragma unroll
    for (int m = 32; m >= 1; m >>= 1) ss += __shfl_xor(ss, m);
    v = v / fmaxf(sqrtf(ss), 1e-12f);
    v += type_emb[(n >= ENT_OFFSET ? 1 : 0) * 64 + lane];

    all_e[n * 160 + lane] = v;
}

// ---------------- SpMM: side[r] += v * x[c]  (one wave per edge) ----------------
__global__ void spmm_kernel(const int* __restrict__ rows,
                            const int* __restrict__ cols,
                            const float* __restrict__ vals, int E,
                            const float* __restrict__ x, int xstride,
                            float* __restrict__ side)           // [N,64], pre-zeroed
{
    int wid  = (blockIdx.x * blockDim.x + threadIdx.x) >> 6;
    int lane = threadIdx.x & 63;
    int nw   = (gridDim.x * blockDim.x) >> 6;
    for (int e = wid; e < E; e += nw) {
        int   r = rows[e];
        int   c = cols[e];
        float v = vals[e];
        atomicAdd(&side[r * 64 + lane], v * x[c * xstride + lane]);
    }
}

// ---------------- Dense conv layer ----------------
// 4 nodes per block (one wave each). lane < OUT computes one output dim.
template <int OUT>
__global__ void layer_kernel(const float* __restrict__ x, int xstride, // ego_in
                             const float* __restrict__ side,           // [N,64]
                             const float* __restrict__ W1, const float* __restrict__ b1,
                             const float* __restrict__ W2, const float* __restrict__ b2,
                             float* __restrict__ ego_out,              // [N,64] or null
                             float* __restrict__ all_e, int out_off)   // l2norm'd out
{
    __shared__ float s_sum[4][64];
    __shared__ float s_bi[4][64];
    int local = threadIdx.x >> 6;
    int lane  = threadIdx.x & 63;
    int n     = blockIdx.x * 4 + local;

    float xe = x[n * xstride + lane];
    float sd = side[n * 64 + lane];
    s_sum[local][lane] = xe + sd;
    s_bi[local][lane]  = xe * sd;
    __syncthreads();

    float eo = 0.0f;
    if (lane < OUT) {
        float acc1 = b1[lane];
        float acc2 = b2[lane];
        #pragma unroll
        for (int d = 0; d < 64; d++) {
            acc1 += s_sum[local][d] * W1[lane * 64 + d];
            acc2 += s_bi[local][d]  * W2[lane * 64 + d];
        }
        acc1 = acc1 > 0.0f ? acc1 : 0.01f * acc1;
        acc2 = acc2 > 0.0f ? acc2 : 0.01f * acc2;
        eo = acc1 + acc2;
    }

    float ss = eo * eo;
    #pragma unroll
    for (int m = 32; m >= 1; m >>= 1) ss += __shfl_xor(ss, m);
    float nv = eo / fmaxf(sqrtf(ss), 1e-12f);

    if (lane < OUT) {
        all_e[n * 160 + out_off + lane] = nv;
        if (ego_out) ego_out[n * 64 + lane] = eo;   // unnormalized feeds next layer
    }
}

// ---------------- Score GEMM: out[i,j] = dot(all_e[u[i]], all_e[it[j]]) ----------------
__global__ void score_kernel(const float* __restrict__ all_e,
                             const int* __restrict__ uids,
                             const int* __restrict__ iids,
                             float* __restrict__ out, int n_items)
{
    __shared__ float Ut[16][161];
    __shared__ float Vt[16][161];
    int i0 = blockIdx.y * 16;
    int j0 = blockIdx.x * 16;

    for (int t = threadIdx.x; t < 16 * 160; t += 256) {
        int r = t / 160, c = t - r * 160;
        Ut[r][c] = all_e[uids[i0 + r] * 160 + c];
        Vt[r][c] = all_e[iids[j0 + r] * 160 + c];
    }
    __syncthreads();

    int ty = threadIdx.x >> 4;
    int tx = threadIdx.x & 15;
    float acc = 0.0f;
    #pragma unroll
    for (int k = 0; k < 160; k++) acc += Ut[ty][k] * Vt[tx][k];
    out[(i0 + ty) * n_items + (j0 + tx)] = acc;
}

extern "C" void kernel_launch(void* const* d_in, const int* in_sizes, int n_in,
                              void* d_out, int out_size, void* d_ws, size_t ws_size,
                              hipStream_t stream) {
    const int*   user_ids = (const int*)  d_in[0];
    const int*   item_ids = (const int*)  d_in[1];
    const float* aux      = (const float*)d_in[2];
    const int*   A_rows   = (const int*)  d_in[3];
    const int*   A_cols   = (const int*)  d_in[4];
    const float* A_vals   = (const float*)d_in[5];
    const float* entity   = (const float*)d_in[6];
    const float* type_emb = (const float*)d_in[7];
    const float* W_aux    = (const float*)d_in[8];
    const float* b_aux    = (const float*)d_in[9];
    const float* W1_0     = (const float*)d_in[10];
    const float* b1_0     = (const float*)d_in[11];
    const float* W2_0     = (const float*)d_in[12];
    const float* b2_0     = (const float*)d_in[13];
    const float* W1_1     = (const float*)d_in[14];
    const float* b1_1     = (const float*)d_in[15];
    const float* W2_1     = (const float*)d_in[16];
    const float* b2_1     = (const float*)d_in[17];

    int E       = in_sizes[3];
    int n_users = in_sizes[0];
    int n_items = in_sizes[1];

    char*  ws    = (char*)d_ws;
    float* all_e = (float*)(ws);                                    // N*160 f32
    float* ego   = (float*)(ws + (size_t)NN * 160 * 4);             // N*64  f32
    float* side  = (float*)(ws + (size_t)NN * 160 * 4
                               + (size_t)NN * 64  * 4);             // N*64  f32

    // Stage A
    fuse_kernel<<<NN / 4, 256, 0, stream>>>(aux, entity, type_emb, W_aux, b_aux, all_e);

    // Layer 0
    hipMemsetAsync(side, 0, (size_t)NN * 64 * 4, stream);
    spmm_kernel<<<2048, 256, 0, stream>>>(A_rows, A_cols, A_vals, E, all_e, 160, side);
    layer_kernel<64><<<NN / 4, 256, 0, stream>>>(all_e, 160, side,
                                                 W1_0, b1_0, W2_0, b2_0,
                                                 ego, all_e, 64);

    // Layer 1
    hipMemsetAsync(side, 0, (size_t)NN * 64 * 4, stream);
    spmm_kernel<<<2048, 256, 0, stream>>>(A_rows, A_cols, A_vals, E, ego, 64, side);
    layer_kernel<32><<<NN / 4, 256, 0, stream>>>(ego, 64, side,
                                                 W1_1, b1_1, W2_1, b2_1,
                                                 nullptr, all_e, 128);

    // Score
    dim3 sgrid(n_items / 16, n_users / 16);
    score_kernel<<<sgrid, 256, 0, stream>>>(all_e, user_ids, item_ids,
                                            (float*)d_out, n_items);
}

// Round 2
// 913.369 us; speedup vs baseline: 1.5786x; 1.5786x over previous
//
#include <hip/hip_runtime.h>
#include <math.h>

#define NN 100000
#define DIM 64
#define ENT_OFFSET 20000
#define PAD 68   // LDS row pad (multiple of 4 for b128 alignment)

// ---------------- Stage A: holographic fusion ----------------
__global__ void fuse_kernel(const float* __restrict__ aux,      // [N,3]
                            const float* __restrict__ entity,   // [N,64]
                            const float* __restrict__ type_emb, // [2,64]
                            const float* __restrict__ W_aux,    // [64,3]
                            const float* __restrict__ b_aux,    // [64]
                            float* __restrict__ all_e)          // [N,160], cols 0..63
{
    int n    = blockIdx.x * 4 + (threadIdx.x >> 6);
    int lane = threadIdx.x & 63;

    float a0 = log1pf(aux[n * 3 + 0]);
    float a1 = log1pf(aux[n * 3 + 1]);
    float a2 = log1pf(aux[n * 3 + 2]);
    float g  = a0 * W_aux[lane * 3 + 0] + a1 * W_aux[lane * 3 + 1]
             + a2 * W_aux[lane * 3 + 2] + b_aux[lane];
    g = 1.0f / (1.0f + expf(-g)) * 0.15f + 1.0f;

    float v  = entity[n * 64 + lane] * g;
    float ss = v * v;
    #pragma unroll
    for (int m = 32; m >= 1; m >>= 1) ss += __shfl_xor(ss, m);
    v = v / fmaxf(sqrtf(ss), 1e-12f);
    v += type_emb[(n >= ENT_OFFSET ? 1 : 0) * 64 + lane];

    all_e[n * 160 + lane] = v;
}

// ---------------- SpMM: side[r] += v * x[c]  (one wave per edge) ----------------
__global__ void spmm_kernel(const int* __restrict__ rows,
                            const int* __restrict__ cols,
                            const float* __restrict__ vals, int E,
                            const float* __restrict__ x, int xstride,
                            float* __restrict__ side)           // [N,64], pre-zeroed
{
    int wid  = (blockIdx.x * blockDim.x + threadIdx.x) >> 6;
    int lane = threadIdx.x & 63;
    int nw   = (gridDim.x * blockDim.x) >> 6;
    for (int e = wid; e < E; e += nw) {
        int   r = rows[e];
        int   c = cols[e];
        float v = vals[e];
        atomicAdd(&side[r * 64 + lane], v * x[c * xstride + lane]);
    }
}

// ---------------- Dense conv layer v2 ----------------
// 64 nodes per block. W1,W2 staged in LDS (row pad 68). Thread t handles
// 2 consecutive nodes (nb = t>>3) and OUT/8 output dims (o = (t&7) + 8*i).
template <int OUT>
__global__ __launch_bounds__(256) void layer_kernel(
    const float* __restrict__ x, int xstride,
    const float* __restrict__ side,
    const float* __restrict__ W1, const float* __restrict__ b1,
    const float* __restrict__ W2, const float* __restrict__ b2,
    float* __restrict__ ego_out,               // unnormalized, or null
    float* __restrict__ all_e, int out_off)    // l2norm'd into [N,160]
{
    constexpr int OPT = OUT / 8;
    __shared__ float W1s[OUT * PAD];
    __shared__ float W2s[OUT * PAD];
    __shared__ float s_sum[64 * PAD];
    __shared__ float s_bi [64 * PAD];

    int tid = threadIdx.x;
    int n0  = blockIdx.x * 64;

    for (int t = tid; t < OUT * 64; t += 256) {
        int r = t >> 6, c = t & 63;
        W1s[r * PAD + c] = W1[t];
        W2s[r * PAD + c] = W2[t];
    }
    for (int t = tid; t < 64 * 64; t += 256) {
        int n = t >> 6, d = t & 63;
        int gn = n0 + n;
        float xe = 0.0f, sd = 0.0f;
        if (gn < NN) {
            xe = x[(size_t)gn * xstride + d];
            sd = side[gn * 64 + d];
        }
        s_sum[n * PAD + d] = xe + sd;
        s_bi [n * PAD + d] = xe * sd;
    }
    __syncthreads();

    int og = tid & 7;
    int nb = tid >> 3;
    int nA = nb * 2, nB = nA + 1;

    float acc1[2][OPT], acc2[2][OPT];
    #pragma unroll
    for (int i = 0; i < OPT; i++) {
        int o = og + 8 * i;
        acc1[0][i] = b1[o]; acc1[1][i] = b1[o];
        acc2[0][i] = b2[o]; acc2[1][i] = b2[o];
    }

    #pragma unroll 4
    for (int d4 = 0; d4 < 16; d4++) {
        float4 sA = *(const float4*)&s_sum[nA * PAD + d4 * 4];
        float4 bA = *(const float4*)&s_bi [nA * PAD + d4 * 4];
        float4 sB = *(const float4*)&s_sum[nB * PAD + d4 * 4];
        float4 bB = *(const float4*)&s_bi [nB * PAD + d4 * 4];
        #pragma unroll
        for (int i = 0; i < OPT; i++) {
            int o = og + 8 * i;
            float4 w1 = *(const float4*)&W1s[o * PAD + d4 * 4];
            float4 w2 = *(const float4*)&W2s[o * PAD + d4 * 4];
            acc1[0][i] += sA.x * w1.x + sA.y * w1.y + sA.z * w1.z + sA.w * w1.w;
            acc1[1][i] += sB.x * w1.x + sB.y * w1.y + sB.z * w1.z + sB.w * w1.w;
            acc2[0][i] += bA.x * w2.x + bA.y * w2.y + bA.z * w2.z + bA.w * w2.w;
            acc2[1][i] += bB.x * w2.x + bB.y * w2.y + bB.z * w2.z + bB.w * w2.w;
        }
    }

    float eo[2][OPT];
    float ss0 = 0.0f, ss1 = 0.0f;
    #pragma unroll
    for (int i = 0; i < OPT; i++) {
        float a = acc1[0][i]; a = a > 0.0f ? a : 0.01f * a;
        float c = acc2[0][i]; c = c > 0.0f ? c : 0.01f * c;
        eo[0][i] = a + c; ss0 += eo[0][i] * eo[0][i];
        a = acc1[1][i]; a = a > 0.0f ? a : 0.01f * a;
        c = acc2[1][i]; c = c > 0.0f ? c : 0.01f * c;
        eo[1][i] = a + c; ss1 += eo[1][i] * eo[1][i];
    }
    #pragma unroll
    for (int m = 1; m <= 4; m <<= 1) {
        ss0 += __shfl_xor(ss0, m);
        ss1 += __shfl_xor(ss1, m);
    }
    float inv0 = 1.0f / fmaxf(sqrtf(ss0), 1e-12f);
    float inv1 = 1.0f / fmaxf(sqrtf(ss1), 1e-12f);

    int gnA = n0 + nA, gnB = n0 + nB;
    #pragma unroll
    for (int i = 0; i < OPT; i++) {
        int o = og + 8 * i;
        if (gnA < NN) {
            all_e[(size_t)gnA * 160 + out_off + o] = eo[0][i] * inv0;
            if (ego_out) ego_out[gnA * 64 + o] = eo[0][i];
        }
        if (gnB < NN) {
            all_e[(size_t)gnB * 160 + out_off + o] = eo[1][i] * inv1;
            if (ego_out) ego_out[gnB * 64 + o] = eo[1][i];
        }
    }
}

// ---------------- Score GEMM v2: 64x64 tile, 4x4 register blocking ----------------
__global__ __launch_bounds__(256) void score_kernel(
    const float* __restrict__ all_e,
    const int* __restrict__ uids,
    const int* __restrict__ iids,
    float* __restrict__ out, int n_items)
{
    __shared__ float Us[64 * 36];
    __shared__ float Vs[64 * 36];
    int i0 = blockIdx.y * 64;
    int j0 = blockIdx.x * 64;
    int tid = threadIdx.x;
    int tx = tid & 15, ty = tid >> 4;

    float acc[4][4];
    #pragma unroll
    for (int a = 0; a < 4; a++)
        #pragma unroll
        for (int b = 0; b < 4; b++) acc[a][b] = 0.0f;

    for (int kc = 0; kc < 160; kc += 32) {
        __syncthreads();
        for (int t = tid; t < 64 * 32; t += 256) {
            int r = t >> 5, c = t & 31;
            Us[r * 36 + c] = all_e[(size_t)uids[i0 + r] * 160 + kc + c];
            Vs[r * 36 + c] = all_e[(size_t)iids[j0 + r] * 160 + kc + c];
        }
        __syncthreads();
        #pragma unroll
        for (int k4 = 0; k4 < 8; k4++) {
            float4 u[4], v[4];
            #pragma unroll
            for (int a = 0; a < 4; a++) {
                u[a] = *(const float4*)&Us[(ty + 16 * a) * 36 + k4 * 4];
                v[a] = *(const float4*)&Vs[(tx + 16 * a) * 36 + k4 * 4];
            }
            #pragma unroll
            for (int a = 0; a < 4; a++)
                #pragma unroll
                for (int b = 0; b < 4; b++)
                    acc[a][b] += u[a].x * v[b].x + u[a].y * v[b].y
                               + u[a].z * v[b].z + u[a].w * v[b].w;
        }
    }
    #pragma unroll
    for (int a = 0; a < 4; a++) {
        int i = i0 + ty + 16 * a;
        #pragma unroll
        for (int b = 0; b < 4; b++) {
            int j = j0 + tx + 16 * b;
            out[(size_t)i * n_items + j] = acc[a][b];
        }
    }
}

extern "C" void kernel_launch(void* const* d_in, const int* in_sizes, int n_in,
                              void* d_out, int out_size, void* d_ws, size_t ws_size,
                              hipStream_t stream) {
    const int*   user_ids = (const int*)  d_in[0];
    const int*   item_ids = (const int*)  d_in[1];
    const float* aux      = (const float*)d_in[2];
    const int*   A_rows   = (const int*)  d_in[3];
    const int*   A_cols   = (const int*)  d_in[4];
    const float* A_vals   = (const float*)d_in[5];
    const float* entity   = (const float*)d_in[6];
    const float* type_emb = (const float*)d_in[7];
    const float* W_aux    = (const float*)d_in[8];
    const float* b_aux    = (const float*)d_in[9];
    const float* W1_0     = (const float*)d_in[10];
    const float* b1_0     = (const float*)d_in[11];
    const float* W2_0     = (const float*)d_in[12];
    const float* b2_0     = (const float*)d_in[13];
    const float* W1_1     = (const float*)d_in[14];
    const float* b1_1     = (const float*)d_in[15];
    const float* W2_1     = (const float*)d_in[16];
    const float* b2_1     = (const float*)d_in[17];

    int E       = in_sizes[3];
    int n_users = in_sizes[0];
    int n_items = in_sizes[1];

    char*  ws    = (char*)d_ws;
    float* all_e = (float*)(ws);                                    // N*160 f32
    float* ego   = (float*)(ws + (size_t)NN * 160 * 4);             // N*64  f32
    float* side  = (float*)(ws + (size_t)NN * 160 * 4
                               + (size_t)NN * 64  * 4);             // N*64  f32

    // Stage A
    fuse_kernel<<<NN / 4, 256, 0, stream>>>(aux, entity, type_emb, W_aux, b_aux, all_e);

    int lgrid = (NN + 63) / 64;

    // Layer 0
    hipMemsetAsync(side, 0, (size_t)NN * 64 * 4, stream);
    spmm_kernel<<<2048, 256, 0, stream>>>(A_rows, A_cols, A_vals, E, all_e, 160, side);
    layer_kernel<64><<<lgrid, 256, 0, stream>>>(all_e, 160, side,
                                                W1_0, b1_0, W2_0, b2_0,
                                                ego, all_e, 64);

    // Layer 1
    hipMemsetAsync(side, 0, (size_t)NN * 64 * 4, stream);
    spmm_kernel<<<2048, 256, 0, stream>>>(A_rows, A_cols, A_vals, E, ego, 64, side);
    layer_kernel<32><<<lgrid, 256, 0, stream>>>(ego, 64, side,
                                                W1_1, b1_1, W2_1, b2_1,
                                                nullptr, all_e, 128);

    // Score
    dim3 sgrid(n_items / 64, n_users / 64);
    score_kernel<<<sgrid, 256, 0, stream>>>(all_e, user_ids, item_ids,
                                            (float*)d_out, n_items);
}

// Round 3
// 561.529 us; speedup vs baseline: 2.5677x; 1.6266x over previous
//
#include <hip/hip_runtime.h>
#include <math.h>

#define NN 100000
#define DIM 64
#define ENT_OFFSET 20000
#define PAD 68   // LDS row pad

// ---------------- Stage A: holographic fusion ----------------
__global__ void fuse_kernel(const float* __restrict__ aux,
                            const float* __restrict__ entity,
                            const float* __restrict__ type_emb,
                            const float* __restrict__ W_aux,
                            const float* __restrict__ b_aux,
                            float* __restrict__ all_e)          // [N,160], cols 0..63
{
    int n    = blockIdx.x * 4 + (threadIdx.x >> 6);
    int lane = threadIdx.x & 63;

    float a0 = log1pf(aux[n * 3 + 0]);
    float a1 = log1pf(aux[n * 3 + 1]);
    float a2 = log1pf(aux[n * 3 + 2]);
    float g  = a0 * W_aux[lane * 3 + 0] + a1 * W_aux[lane * 3 + 1]
             + a2 * W_aux[lane * 3 + 2] + b_aux[lane];
    g = 1.0f / (1.0f + expf(-g)) * 0.15f + 1.0f;

    float v  = entity[n * 64 + lane] * g;
    float ss = v * v;
    #pragma unroll
    for (int m = 32; m >= 1; m >>= 1) ss += __shfl_xor(ss, m);
    v = v / fmaxf(sqrtf(ss), 1e-12f);
    v += type_emb[(n >= ENT_OFFSET ? 1 : 0) * 64 + lane];

    all_e[n * 160 + lane] = v;
}

// ---------------- CSR build: histogram -> scan -> scatter ----------------
__global__ void hist_kernel(const int* __restrict__ rows, int E, int* __restrict__ cnt)
{
    int i = blockIdx.x * blockDim.x + threadIdx.x;
    int s = gridDim.x * blockDim.x;
    for (; i < E; i += s) atomicAdd(&cnt[rows[i]], 1);
}

// block b scans 1024 counters (4/thread); writes block-local exclusive scan + block total
__global__ __launch_bounds__(256) void scan1_kernel(const int* __restrict__ cnt,
                                                    int* __restrict__ rowptr,
                                                    int* __restrict__ bsum)
{
    __shared__ int lds[256];
    int b = blockIdx.x, t = threadIdx.x;
    int base = b * 1024 + t * 4;
    int c[4];
    #pragma unroll
    for (int k = 0; k < 4; k++) {
        int i = base + k;
        c[k] = (i < NN) ? cnt[i] : 0;
    }
    int s = c[0] + c[1] + c[2] + c[3];
    lds[t] = s;
    __syncthreads();
    for (int off = 1; off < 256; off <<= 1) {
        int v = (t >= off) ? lds[t - off] : 0;
        __syncthreads();
        lds[t] += v;
        __syncthreads();
    }
    int run = lds[t] - s;            // exclusive prefix within block
    if (t == 255) bsum[b] = lds[255];
    #pragma unroll
    for (int k = 0; k < 4; k++) {
        int i = base + k;
        if (i < NN) rowptr[i] = run;
        run += c[k];
    }
}

__global__ void scan2_kernel(int* __restrict__ bsum, int nb)
{
    __shared__ int lds[128];
    int t = threadIdx.x;
    int v = (t < nb) ? bsum[t] : 0;
    lds[t] = v;
    __syncthreads();
    for (int off = 1; off < 128; off <<= 1) {
        int u = (t >= off) ? lds[t - off] : 0;
        __syncthreads();
        lds[t] += u;
        __syncthreads();
    }
    if (t < nb) bsum[t] = lds[t] - v;  // exclusive
}

__global__ void scan3_kernel(int* __restrict__ rowptr, const int* __restrict__ bsum, int E)
{
    int i = blockIdx.x * blockDim.x + threadIdx.x;
    if (i < NN) rowptr[i] += bsum[i >> 10];
    if (i == NN) rowptr[NN] = E;
}

__global__ void scatter_kernel(const int* __restrict__ rows, const int* __restrict__ cols,
                               const float* __restrict__ vals, int E,
                               const int* __restrict__ rowptr, int* __restrict__ cnt,
                               uint2* __restrict__ cv)
{
    int i = blockIdx.x * blockDim.x + threadIdx.x;
    int s = gridDim.x * blockDim.x;
    for (; i < E; i += s) {
        int r = rows[i];
        int pos = rowptr[r] + atomicAdd(&cnt[r], 1);
        cv[pos] = make_uint2((unsigned)cols[i], __float_as_uint(vals[i]));
    }
}

// ---------------- SpMM (CSR): one wave per row, no atomics ----------------
template <int STR>
__global__ __launch_bounds__(256) void spmm_csr_kernel(
    const int* __restrict__ rowptr, const uint2* __restrict__ cv,
    const float* __restrict__ x, float* __restrict__ side)
{
    int r = (blockIdx.x * blockDim.x + threadIdx.x) >> 6;
    if (r >= NN) return;
    int lane = threadIdx.x & 63;
    int s = rowptr[r], e = rowptr[r + 1];

    float acc = 0.0f;
    int i = s;
    for (; i + 4 <= e; i += 4) {
        uint2 e0 = cv[i],     e1 = cv[i + 1];
        uint2 e2 = cv[i + 2], e3 = cv[i + 3];
        float x0 = x[(size_t)e0.x * STR + lane];
        float x1 = x[(size_t)e1.x * STR + lane];
        float x2 = x[(size_t)e2.x * STR + lane];
        float x3 = x[(size_t)e3.x * STR + lane];
        acc += __uint_as_float(e0.y) * x0 + __uint_as_float(e1.y) * x1
             + __uint_as_float(e2.y) * x2 + __uint_as_float(e3.y) * x3;
    }
    for (; i < e; i++) {
        uint2 e0 = cv[i];
        acc += __uint_as_float(e0.y) * x[(size_t)e0.x * STR + lane];
    }
    side[r * 64 + lane] = acc;
}

// ---------------- Dense conv layer ----------------
// NORM=true: write l2-normalized outputs. NORM=false: write raw + inv-norm scale.
template <int OUT, bool NORM>
__global__ __launch_bounds__(256) void layer_kernel(
    const float* __restrict__ x, int xstride,
    const float* __restrict__ side,
    const float* __restrict__ W1, const float* __restrict__ b1,
    const float* __restrict__ W2, const float* __restrict__ b2,
    float* __restrict__ all_e, int out_off,
    float* __restrict__ scale_out)
{
    constexpr int OPT = OUT / 8;
    __shared__ float W1s[OUT * PAD];
    __shared__ float W2s[OUT * PAD];
    __shared__ float s_sum[64 * PAD];
    __shared__ float s_bi [64 * PAD];

    int tid = threadIdx.x;
    int n0  = blockIdx.x * 64;

    for (int t = tid; t < OUT * 64; t += 256) {
        int r = t >> 6, c = t & 63;
        W1s[r * PAD + c] = W1[t];
        W2s[r * PAD + c] = W2[t];
    }
    for (int t = tid; t < 64 * 64; t += 256) {
        int n = t >> 6, d = t & 63;
        int gn = n0 + n;
        float xe = 0.0f, sd = 0.0f;
        if (gn < NN) {
            xe = x[(size_t)gn * xstride + d];
            sd = side[gn * 64 + d];
        }
        s_sum[n * PAD + d] = xe + sd;
        s_bi [n * PAD + d] = xe * sd;
    }
    __syncthreads();

    int og = tid & 7;
    int nb = tid >> 3;
    int nA = nb * 2, nB = nA + 1;

    float acc1[2][OPT], acc2[2][OPT];
    #pragma unroll
    for (int i = 0; i < OPT; i++) {
        int o = og + 8 * i;
        acc1[0][i] = b1[o]; acc1[1][i] = b1[o];
        acc2[0][i] = b2[o]; acc2[1][i] = b2[o];
    }

    #pragma unroll 4
    for (int d4 = 0; d4 < 16; d4++) {
        float4 sA = *(const float4*)&s_sum[nA * PAD + d4 * 4];
        float4 bA = *(const float4*)&s_bi [nA * PAD + d4 * 4];
        float4 sB = *(const float4*)&s_sum[nB * PAD + d4 * 4];
        float4 bB = *(const float4*)&s_bi [nB * PAD + d4 * 4];
        #pragma unroll
        for (int i = 0; i < OPT; i++) {
            int o = og + 8 * i;
            float4 w1 = *(const float4*)&W1s[o * PAD + d4 * 4];
            float4 w2 = *(const float4*)&W2s[o * PAD + d4 * 4];
            acc1[0][i] += sA.x * w1.x + sA.y * w1.y + sA.z * w1.z + sA.w * w1.w;
            acc1[1][i] += sB.x * w1.x + sB.y * w1.y + sB.z * w1.z + sB.w * w1.w;
            acc2[0][i] += bA.x * w2.x + bA.y * w2.y + bA.z * w2.z + bA.w * w2.w;
            acc2[1][i] += bB.x * w2.x + bB.y * w2.y + bB.z * w2.z + bB.w * w2.w;
        }
    }

    float eo[2][OPT];
    float ss0 = 0.0f, ss1 = 0.0f;
    #pragma unroll
    for (int i = 0; i < OPT; i++) {
        float a = acc1[0][i]; a = a > 0.0f ? a : 0.01f * a;
        float c = acc2[0][i]; c = c > 0.0f ? c : 0.01f * c;
        eo[0][i] = a + c; ss0 += eo[0][i] * eo[0][i];
        a = acc1[1][i]; a = a > 0.0f ? a : 0.01f * a;
        c = acc2[1][i]; c = c > 0.0f ? c : 0.01f * c;
        eo[1][i] = a + c; ss1 += eo[1][i] * eo[1][i];
    }
    #pragma unroll
    for (int m = 1; m <= 4; m <<= 1) {
        ss0 += __shfl_xor(ss0, m);
        ss1 += __shfl_xor(ss1, m);
    }
    float inv0 = 1.0f / fmaxf(sqrtf(ss0), 1e-12f);
    float inv1 = 1.0f / fmaxf(sqrtf(ss1), 1e-12f);

    int gnA = n0 + nA, gnB = n0 + nB;
    #pragma unroll
    for (int i = 0; i < OPT; i++) {
        int o = og + 8 * i;
        if (gnA < NN) {
            if (NORM) all_e[(size_t)gnA * 160 + out_off + o] = eo[0][i] * inv0;
            else      all_e[(size_t)gnA * 160 + out_off + o] = eo[0][i];
        }
        if (gnB < NN) {
            if (NORM) all_e[(size_t)gnB * 160 + out_off + o] = eo[1][i] * inv1;
            else      all_e[(size_t)gnB * 160 + out_off + o] = eo[1][i];
        }
    }
    if (!NORM && og == 0) {
        if (gnA < NN) scale_out[gnA] = inv0;
        if (gnB < NN) scale_out[gnB] = inv1;
    }
}

// ---------------- Score GEMM: 64x64 tile, 4x4 register blocking ----------------
// cols 64..127 of all_e hold UNNORMALIZED ego1; multiply by scale1[node] on load.
__global__ __launch_bounds__(256) void score_kernel(
    const float* __restrict__ all_e,
    const float* __restrict__ scale1,
    const int* __restrict__ uids,
    const int* __restrict__ iids,
    float* __restrict__ out, int n_items)
{
    __shared__ float Us[64 * 36];
    __shared__ float Vs[64 * 36];
    int i0 = blockIdx.y * 64;
    int j0 = blockIdx.x * 64;
    int tid = threadIdx.x;
    int tx = tid & 15, ty = tid >> 4;

    float acc[4][4];
    #pragma unroll
    for (int a = 0; a < 4; a++)
        #pragma unroll
        for (int b = 0; b < 4; b++) acc[a][b] = 0.0f;

    for (int kc = 0; kc < 160; kc += 32) {
        bool scaled = (kc == 64 || kc == 96);
        __syncthreads();
        for (int t = tid; t < 64 * 32; t += 256) {
            int r = t >> 5, c = t & 31;
            int uid = uids[i0 + r];
            int iid = iids[j0 + r];
            float su = scaled ? scale1[uid] : 1.0f;
            float si = scaled ? scale1[iid] : 1.0f;
            Us[r * 36 + c] = all_e[(size_t)uid * 160 + kc + c] * su;
            Vs[r * 36 + c] = all_e[(size_t)iid * 160 + kc + c] * si;
        }
        __syncthreads();
        #pragma unroll
        for (int k4 = 0; k4 < 8; k4++) {
            float4 u[4], v[4];
            #pragma unroll
            for (int a = 0; a < 4; a++) {
                u[a] = *(const float4*)&Us[(ty + 16 * a) * 36 + k4 * 4];
                v[a] = *(const float4*)&Vs[(tx + 16 * a) * 36 + k4 * 4];
            }
            #pragma unroll
            for (int a = 0; a < 4; a++)
                #pragma unroll
                for (int b = 0; b < 4; b++)
                    acc[a][b] += u[a].x * v[b].x + u[a].y * v[b].y
                               + u[a].z * v[b].z + u[a].w * v[b].w;
        }
    }
    #pragma unroll
    for (int a = 0; a < 4; a++) {
        int i = i0 + ty + 16 * a;
        #pragma unroll
        for (int b = 0; b < 4; b++) {
            int j = j0 + tx + 16 * b;
            out[(size_t)i * n_items + j] = acc[a][b];
        }
    }
}

extern "C" void kernel_launch(void* const* d_in, const int* in_sizes, int n_in,
                              void* d_out, int out_size, void* d_ws, size_t ws_size,
                              hipStream_t stream) {
    const int*   user_ids = (const int*)  d_in[0];
    const int*   item_ids = (const int*)  d_in[1];
    const float* aux      = (const float*)d_in[2];
    const int*   A_rows   = (const int*)  d_in[3];
    const int*   A_cols   = (const int*)  d_in[4];
    const float* A_vals   = (const float*)d_in[5];
    const float* entity   = (const float*)d_in[6];
    const float* type_emb = (const float*)d_in[7];
    const float* W_aux    = (const float*)d_in[8];
    const float* b_aux    = (const float*)d_in[9];
    const float* W1_0     = (const float*)d_in[10];
    const float* b1_0     = (const float*)d_in[11];
    const float* W2_0     = (const float*)d_in[12];
    const float* b2_0     = (const float*)d_in[13];
    const float* W1_1     = (const float*)d_in[14];
    const float* b1_1     = (const float*)d_in[15];
    const float* W2_1     = (const float*)d_in[16];
    const float* b2_1     = (const float*)d_in[17];

    int E       = in_sizes[3];
    int n_users = in_sizes[0];
    int n_items = in_sizes[1];

    char* ws = (char*)d_ws;
    size_t off = 0;
    float* all_e  = (float*)(ws + off); off += (size_t)NN * 160 * 4;   // 64.0 MB
    float* side   = (float*)(ws + off); off += (size_t)NN * 64 * 4;    // 25.6 MB
    float* scale1 = (float*)(ws + off); off += (size_t)NN * 4;         // 0.4 MB
    int*   rowptr = (int*)  (ws + off); off += (size_t)(NN + 1) * 4;   // 0.4 MB
    int*   cnt    = (int*)  (ws + off); off += (size_t)NN * 4;         // 0.4 MB
    int*   bsum   = (int*)  (ws + off); off += 512;
    uint2* cv     = (uint2*)(ws + off); off += (size_t)E * 8;          // 12.8 MB

    const int NB = (NN + 1023) / 1024;   // 98 scan blocks

    // ---- CSR build (once, reused by both layers) ----
    hipMemsetAsync(cnt, 0, (size_t)NN * 4, stream);
    hist_kernel<<<2048, 256, 0, stream>>>(A_rows, E, cnt);
    scan1_kernel<<<NB, 256, 0, stream>>>(cnt, rowptr, bsum);
    scan2_kernel<<<1, 128, 0, stream>>>(bsum, NB);
    scan3_kernel<<<(NN + 256) / 256, 256, 0, stream>>>(rowptr, bsum, E);
    hipMemsetAsync(cnt, 0, (size_t)NN * 4, stream);
    scatter_kernel<<<2048, 256, 0, stream>>>(A_rows, A_cols, A_vals, E, rowptr, cnt, cv);

    // ---- Stage A ----
    fuse_kernel<<<NN / 4, 256, 0, stream>>>(aux, entity, type_emb, W_aux, b_aux, all_e);

    int lgrid = (NN + 63) / 64;
    int sgrid_rows = (NN + 3) / 4;

    // ---- Layer 0: ego0 = all_e[:,0:64] (stride 160) ----
    spmm_csr_kernel<160><<<sgrid_rows, 256, 0, stream>>>(rowptr, cv, all_e, side);
    layer_kernel<64, false><<<lgrid, 256, 0, stream>>>(all_e, 160, side,
                                                       W1_0, b1_0, W2_0, b2_0,
                                                       all_e, 64, scale1);

    // ---- Layer 1: ego1 (unnormalized) = all_e[:,64:128] (stride 160) ----
    spmm_csr_kernel<160><<<sgrid_rows, 256, 0, stream>>>(rowptr, cv, all_e + 64, side);
    layer_kernel<32, true><<<lgrid, 256, 0, stream>>>(all_e + 64, 160, side,
                                                      W1_1, b1_1, W2_1, b2_1,
                                                      all_e, 128, nullptr);

    // ---- Score ----
    dim3 sgrid(n_items / 64, n_users / 64);
    score_kernel<<<sgrid, 256, 0, stream>>>(all_e, scale1, user_ids, item_ids,
                                            (float*)d_out, n_items);
}

// Round 4
// 438.843 us; speedup vs baseline: 3.2855x; 1.2796x over previous
//
#include <hip/hip_runtime.h>
#include <math.h>

#define NN 100000
#define DIM 64
#define ENT_OFFSET 20000
#define PAD 68      // LDS row pad
#define BSH 7       // 128 rows per bucket
#define NBK 782     // ceil(100000/128)
#define TILE_C 8192
#define CAPD 8192

// ---------------- Stage A: holographic fusion -> e0 [N,64] ----------------
__global__ void fuse_kernel(const float* __restrict__ aux,
                            const float* __restrict__ entity,
                            const float* __restrict__ type_emb,
                            const float* __restrict__ W_aux,
                            const float* __restrict__ b_aux,
                            float* __restrict__ e0)
{
    int n    = blockIdx.x * 4 + (threadIdx.x >> 6);
    int lane = threadIdx.x & 63;

    float a0 = log1pf(aux[n * 3 + 0]);
    float a1 = log1pf(aux[n * 3 + 1]);
    float a2 = log1pf(aux[n * 3 + 2]);
    float g  = a0 * W_aux[lane * 3 + 0] + a1 * W_aux[lane * 3 + 1]
             + a2 * W_aux[lane * 3 + 2] + b_aux[lane];
    g = 1.0f / (1.0f + expf(-g)) * 0.15f + 1.0f;

    float v  = entity[n * 64 + lane] * g;
    float ss = v * v;
    #pragma unroll
    for (int m = 32; m >= 1; m >>= 1) ss += __shfl_xor(ss, m);
    v = v / fmaxf(sqrtf(ss), 1e-12f);
    v += type_emb[(n >= ENT_OFFSET ? 1 : 0) * 64 + lane];

    e0[n * 64 + lane] = v;
}

// ---------------- CSR build v2: bucketed two-level counting sort ----------------
__global__ void bucket_hist(const int* __restrict__ rows, int E, int* __restrict__ bcnt)
{
    __shared__ int lh[NBK];
    for (int b = threadIdx.x; b < NBK; b += blockDim.x) lh[b] = 0;
    __syncthreads();
    int i = blockIdx.x * blockDim.x + threadIdx.x;
    int s = gridDim.x * blockDim.x;
    for (; i < E; i += s) atomicAdd(&lh[rows[i] >> BSH], 1);
    __syncthreads();
    for (int b = threadIdx.x; b < NBK; b += blockDim.x)
        if (lh[b]) atomicAdd(&bcnt[b], lh[b]);
}

__global__ __launch_bounds__(1024) void bucket_scan(const int* __restrict__ bcnt,
                                                    int* __restrict__ bstart,
                                                    int* __restrict__ bfill,
                                                    int* __restrict__ rowptr, int E)
{
    __shared__ int lds[1024];
    int t = threadIdx.x;
    int v = (t < NBK) ? bcnt[t] : 0;
    lds[t] = v;
    __syncthreads();
    for (int off = 1; off < 1024; off <<= 1) {
        int u = (t >= off) ? lds[t - off] : 0;
        __syncthreads();
        lds[t] += u;
        __syncthreads();
    }
    if (t < NBK) { bstart[t + 1] = lds[t]; bfill[t] = 0; }
    if (t == 0)  { bstart[0] = 0; rowptr[NN] = E; }
}

// Each block claims contiguous runs per bucket -> near-coalesced writes.
// Packs meta = col | (local_row << 17).
__global__ __launch_bounds__(256) void bucket_scatter(
    const int* __restrict__ rows, const int* __restrict__ cols,
    const float* __restrict__ vals, int E,
    const int* __restrict__ bstart, int* __restrict__ bfill,
    uint2* __restrict__ cv)
{
    __shared__ int lhist[NBK];
    __shared__ int gpos[NBK];
    int tid   = threadIdx.x;
    int gbase = blockIdx.x * TILE_C;
    int n     = min(TILE_C, E - gbase);

    for (int b = tid; b < NBK; b += 256) lhist[b] = 0;
    __syncthreads();
    for (int i = tid; i < n; i += 256)
        atomicAdd(&lhist[rows[gbase + i] >> BSH], 1);
    __syncthreads();
    for (int b = tid; b < NBK; b += 256) {
        int c = lhist[b];
        if (c > 0) gpos[b] = bstart[b] + atomicAdd(&bfill[b], c);
        lhist[b] = 0;  // reuse as local fill
    }
    __syncthreads();
    for (int i = tid; i < n; i += 256) {
        int r = rows[gbase + i];
        int b = r >> BSH;
        int ofs = atomicAdd(&lhist[b], 1);
        unsigned meta = (unsigned)cols[gbase + i] | ((unsigned)(r & 127) << 17);
        cv[gpos[b] + ofs] = make_uint2(meta, __float_as_uint(vals[gbase + i]));
    }
}

// One block per bucket: LDS copy, 128-row hist+scan, in-place fine sort + rowptr.
__global__ __launch_bounds__(256) void bucket_sort(
    const int* __restrict__ bstart, uint2* __restrict__ cv, int* __restrict__ rowptr)
{
    __shared__ uint2 raw[CAPD];          // 64 KB
    __shared__ int hist[128], excl[128], fill[128];
    int b = blockIdx.x, tid = threadIdx.x;
    int base = bstart[b];
    int count = bstart[b + 1] - base;

    if (tid < 128) { hist[tid] = 0; fill[tid] = 0; }
    __syncthreads();
    for (int i = tid; i < count && i < CAPD; i += 256) {
        uint2 e = cv[base + i];
        raw[i] = e;
        atomicAdd(&hist[(e.x >> 17) & 127], 1);
    }
    __syncthreads();
    if (tid < 128) excl[tid] = hist[tid];
    __syncthreads();
    for (int off = 1; off < 128; off <<= 1) {
        int v = (tid < 128 && tid >= off) ? excl[tid - off] : 0;
        __syncthreads();
        if (tid < 128) excl[tid] += v;
        __syncthreads();
    }
    if (tid < 128) {
        int ex = excl[tid] - hist[tid];       // inclusive -> exclusive
        excl[tid] = ex;
        int g = (b << BSH) + tid;
        if (g < NN) rowptr[g] = base + ex;
    }
    __syncthreads();
    for (int i = tid; i < count && i < CAPD; i += 256) {
        uint2 e = raw[i];
        int lr = (e.x >> 17) & 127;
        int ofs = excl[lr] + atomicAdd(&fill[lr], 1);
        cv[base + ofs] = make_uint2(e.x & 0x1FFFF, e.y);
    }
}

// ---------------- SpMM (CSR): one wave per row, compact stride-64 input ----------------
__global__ __launch_bounds__(256) void spmm_csr_kernel(
    const int* __restrict__ rowptr, const uint2* __restrict__ cv,
    const float* __restrict__ x, float* __restrict__ side)
{
    int r = (blockIdx.x * blockDim.x + threadIdx.x) >> 6;
    if (r >= NN) return;
    int lane = threadIdx.x & 63;
    int s = rowptr[r], e = rowptr[r + 1];

    float acc = 0.0f;
    int i = s;
    for (; i + 4 <= e; i += 4) {
        uint2 e0 = cv[i],     e1 = cv[i + 1];
        uint2 e2 = cv[i + 2], e3 = cv[i + 3];
        float x0 = x[(size_t)e0.x * 64 + lane];
        float x1 = x[(size_t)e1.x * 64 + lane];
        float x2 = x[(size_t)e2.x * 64 + lane];
        float x3 = x[(size_t)e3.x * 64 + lane];
        acc += __uint_as_float(e0.y) * x0 + __uint_as_float(e1.y) * x1
             + __uint_as_float(e2.y) * x2 + __uint_as_float(e3.y) * x3;
    }
    for (; i < e; i++) {
        uint2 e0 = cv[i];
        acc += __uint_as_float(e0.y) * x[(size_t)e0.x * 64 + lane];
    }
    side[r * 64 + lane] = acc;
}

// ---------------- Dense conv layer (compact outputs) ----------------
// NORM=false: out[N,OUT] raw + scale_out inv-norm. NORM=true: out[N,OUT] normalized.
template <int OUT, bool NORM>
__global__ __launch_bounds__(256) void layer_kernel(
    const float* __restrict__ x,               // [N,64]
    const float* __restrict__ side,            // [N,64]
    const float* __restrict__ W1, const float* __restrict__ b1,
    const float* __restrict__ W2, const float* __restrict__ b2,
    float* __restrict__ out,                   // [N,OUT]
    float* __restrict__ scale_out)
{
    constexpr int OPT = OUT / 8;
    __shared__ float W1s[OUT * PAD];
    __shared__ float W2s[OUT * PAD];
    __shared__ float s_sum[64 * PAD];
    __shared__ float s_bi [64 * PAD];

    int tid = threadIdx.x;
    int n0  = blockIdx.x * 64;

    for (int t = tid; t < OUT * 64; t += 256) {
        int r = t >> 6, c = t & 63;
        W1s[r * PAD + c] = W1[t];
        W2s[r * PAD + c] = W2[t];
    }
    for (int t = tid; t < 64 * 64; t += 256) {
        int n = t >> 6, d = t & 63;
        int gn = n0 + n;
        float xe = 0.0f, sd = 0.0f;
        if (gn < NN) {
            xe = x[(size_t)gn * 64 + d];
            sd = side[gn * 64 + d];
        }
        s_sum[n * PAD + d] = xe + sd;
        s_bi [n * PAD + d] = xe * sd;
    }
    __syncthreads();

    int og = tid & 7;
    int nb = tid >> 3;
    int nA = nb * 2, nB = nA + 1;

    float acc1[2][OPT], acc2[2][OPT];
    #pragma unroll
    for (int i = 0; i < OPT; i++) {
        int o = og + 8 * i;
        acc1[0][i] = b1[o]; acc1[1][i] = b1[o];
        acc2[0][i] = b2[o]; acc2[1][i] = b2[o];
    }

    #pragma unroll 4
    for (int d4 = 0; d4 < 16; d4++) {
        float4 sA = *(const float4*)&s_sum[nA * PAD + d4 * 4];
        float4 bA = *(const float4*)&s_bi [nA * PAD + d4 * 4];
        float4 sB = *(const float4*)&s_sum[nB * PAD + d4 * 4];
        float4 bB = *(const float4*)&s_bi [nB * PAD + d4 * 4];
        #pragma unroll
        for (int i = 0; i < OPT; i++) {
            int o = og + 8 * i;
            float4 w1 = *(const float4*)&W1s[o * PAD + d4 * 4];
            float4 w2 = *(const float4*)&W2s[o * PAD + d4 * 4];
            acc1[0][i] += sA.x * w1.x + sA.y * w1.y + sA.z * w1.z + sA.w * w1.w;
            acc1[1][i] += sB.x * w1.x + sB.y * w1.y + sB.z * w1.z + sB.w * w1.w;
            acc2[0][i] += bA.x * w2.x + bA.y * w2.y + bA.z * w2.z + bA.w * w2.w;
            acc2[1][i] += bB.x * w2.x + bB.y * w2.y + bB.z * w2.z + bB.w * w2.w;
        }
    }

    float eo[2][OPT];
    float ss0 = 0.0f, ss1 = 0.0f;
    #pragma unroll
    for (int i = 0; i < OPT; i++) {
        float a = acc1[0][i]; a = a > 0.0f ? a : 0.01f * a;
        float c = acc2[0][i]; c = c > 0.0f ? c : 0.01f * c;
        eo[0][i] = a + c; ss0 += eo[0][i] * eo[0][i];
        a = acc1[1][i]; a = a > 0.0f ? a : 0.01f * a;
        c = acc2[1][i]; c = c > 0.0f ? c : 0.01f * c;
        eo[1][i] = a + c; ss1 += eo[1][i] * eo[1][i];
    }
    #pragma unroll
    for (int m = 1; m <= 4; m <<= 1) {
        ss0 += __shfl_xor(ss0, m);
        ss1 += __shfl_xor(ss1, m);
    }
    float inv0 = 1.0f / fmaxf(sqrtf(ss0), 1e-12f);
    float inv1 = 1.0f / fmaxf(sqrtf(ss1), 1e-12f);

    int gnA = n0 + nA, gnB = n0 + nB;
    #pragma unroll
    for (int i = 0; i < OPT; i++) {
        int o = og + 8 * i;
        if (gnA < NN) out[(size_t)gnA * OUT + o] = NORM ? eo[0][i] * inv0 : eo[0][i];
        if (gnB < NN) out[(size_t)gnB * OUT + o] = NORM ? eo[1][i] * inv1 : eo[1][i];
    }
    if (!NORM && og == 0) {
        if (gnA < NN) scale_out[gnA] = inv0;
        if (gnB < NN) scale_out[gnB] = inv1;
    }
}

// ---------------- Score GEMM: 64x64 tile, 4x4 register blocking ----------------
__global__ __launch_bounds__(256) void score_kernel(
    const float* __restrict__ e0, const float* __restrict__ e1,
    const float* __restrict__ e2, const float* __restrict__ scale1,
    const int* __restrict__ uids, const int* __restrict__ iids,
    float* __restrict__ out, int n_items)
{
    __shared__ float Us[64 * 36];
    __shared__ float Vs[64 * 36];
    int i0 = blockIdx.y * 64;
    int j0 = blockIdx.x * 64;
    int tid = threadIdx.x;
    int tx = tid & 15, ty = tid >> 4;

    float acc[4][4];
    #pragma unroll
    for (int a = 0; a < 4; a++)
        #pragma unroll
        for (int b = 0; b < 4; b++) acc[a][b] = 0.0f;

    for (int kc = 0; kc < 160; kc += 32) {
        __syncthreads();
        for (int t = tid; t < 64 * 32; t += 256) {
            int r = t >> 5, c = t & 31;
            int uid = uids[i0 + r];
            int iid = iids[j0 + r];
            float u, v;
            if (kc < 64) {
                u = e0[(size_t)uid * 64 + kc + c];
                v = e0[(size_t)iid * 64 + kc + c];
            } else if (kc < 128) {
                u = e1[(size_t)uid * 64 + (kc - 64) + c] * scale1[uid];
                v = e1[(size_t)iid * 64 + (kc - 64) + c] * scale1[iid];
            } else {
                u = e2[(size_t)uid * 32 + (kc - 128) + c];
                v = e2[(size_t)iid * 32 + (kc - 128) + c];
            }
            Us[r * 36 + c] = u;
            Vs[r * 36 + c] = v;
        }
        __syncthreads();
        #pragma unroll
        for (int k4 = 0; k4 < 8; k4++) {
            float4 u[4], v[4];
            #pragma unroll
            for (int a = 0; a < 4; a++) {
                u[a] = *(const float4*)&Us[(ty + 16 * a) * 36 + k4 * 4];
                v[a] = *(const float4*)&Vs[(tx + 16 * a) * 36 + k4 * 4];
            }
            #pragma unroll
            for (int a = 0; a < 4; a++)
                #pragma unroll
                for (int b = 0; b < 4; b++)
                    acc[a][b] += u[a].x * v[b].x + u[a].y * v[b].y
                               + u[a].z * v[b].z + u[a].w * v[b].w;
        }
    }
    #pragma unroll
    for (int a = 0; a < 4; a++) {
        int i = i0 + ty + 16 * a;
        #pragma unroll
        for (int b = 0; b < 4; b++) {
            int j = j0 + tx + 16 * b;
            out[(size_t)i * n_items + j] = acc[a][b];
        }
    }
}

extern "C" void kernel_launch(void* const* d_in, const int* in_sizes, int n_in,
                              void* d_out, int out_size, void* d_ws, size_t ws_size,
                              hipStream_t stream) {
    const int*   user_ids = (const int*)  d_in[0];
    const int*   item_ids = (const int*)  d_in[1];
    const float* aux      = (const float*)d_in[2];
    const int*   A_rows   = (const int*)  d_in[3];
    const int*   A_cols   = (const int*)  d_in[4];
    const float* A_vals   = (const float*)d_in[5];
    const float* entity   = (const float*)d_in[6];
    const float* type_emb = (const float*)d_in[7];
    const float* W_aux    = (const float*)d_in[8];
    const float* b_aux    = (const float*)d_in[9];
    const float* W1_0     = (const float*)d_in[10];
    const float* b1_0     = (const float*)d_in[11];
    const float* W2_0     = (const float*)d_in[12];
    const float* b2_0     = (const float*)d_in[13];
    const float* W1_1     = (const float*)d_in[14];
    const float* b1_1     = (const float*)d_in[15];
    const float* W2_1     = (const float*)d_in[16];
    const float* b2_1     = (const float*)d_in[17];

    int E       = in_sizes[3];
    int n_users = in_sizes[0];
    int n_items = in_sizes[1];

    char* ws = (char*)d_ws;
    size_t off = 0;
    float* e0     = (float*)(ws + off); off += (size_t)NN * 64 * 4;    // 25.6 MB
    float* e1     = (float*)(ws + off); off += (size_t)NN * 64 * 4;    // 25.6 MB
    float* e2     = (float*)(ws + off); off += (size_t)NN * 32 * 4;    // 12.8 MB
    float* side   = (float*)(ws + off); off += (size_t)NN * 64 * 4;    // 25.6 MB
    uint2* cv     = (uint2*)(ws + off); off += (size_t)E * 8;          // 12.8 MB
    float* scale1 = (float*)(ws + off); off += (size_t)NN * 4;
    int*   rowptr = (int*)  (ws + off); off += (size_t)(NN + 1) * 4;
    int*   bcnt   = (int*)  (ws + off); off += (size_t)NBK * 4;
    int*   bstart = (int*)  (ws + off); off += (size_t)(NBK + 1) * 4;
    int*   bfill  = (int*)  (ws + off); off += (size_t)NBK * 4;

    // ---- CSR build v2 (bucketed two-level sort, reused by both layers) ----
    hipMemsetAsync(bcnt, 0, (size_t)NBK * 4, stream);
    bucket_hist<<<512, 256, 0, stream>>>(A_rows, E, bcnt);
    bucket_scan<<<1, 1024, 0, stream>>>(bcnt, bstart, bfill, rowptr, E);
    bucket_scatter<<<(E + TILE_C - 1) / TILE_C, 256, 0, stream>>>(
        A_rows, A_cols, A_vals, E, bstart, bfill, cv);
    bucket_sort<<<NBK, 256, 0, stream>>>(bstart, cv, rowptr);

    // ---- Stage A ----
    fuse_kernel<<<NN / 4, 256, 0, stream>>>(aux, entity, type_emb, W_aux, b_aux, e0);

    int lgrid = (NN + 63) / 64;
    int sgrid_rows = (NN + 3) / 4;

    // ---- Layer 0 ----
    spmm_csr_kernel<<<sgrid_rows, 256, 0, stream>>>(rowptr, cv, e0, side);
    layer_kernel<64, false><<<lgrid, 256, 0, stream>>>(e0, side,
                                                       W1_0, b1_0, W2_0, b2_0,
                                                       e1, scale1);

    // ---- Layer 1 (e1 is unnormalized; reference feeds unnormalized forward) ----
    spmm_csr_kernel<<<sgrid_rows, 256, 0, stream>>>(rowptr, cv, e1, side);
    layer_kernel<32, true><<<lgrid, 256, 0, stream>>>(e1, side,
                                                      W1_1, b1_1, W2_1, b2_1,
                                                      e2, nullptr);

    // ---- Score ----
    dim3 sgrid(n_items / 64, n_users / 64);
    score_kernel<<<sgrid, 256, 0, stream>>>(e0, e1, e2, scale1, user_ids, item_ids,
                                            (float*)d_out, n_items);
}

// Round 5
// 363.484 us; speedup vs baseline: 3.9666x; 1.2073x over previous
//
#include <hip/hip_runtime.h>
#include <math.h>

#define NN 100000
#define DIM 64
#define ENT_OFFSET 20000
#define BSH 7       // 128 rows per bucket
#define NBK 782     // ceil(100000/128)
#define TILE_C 8192
#define CAPD 8192
#define HPAD 68     // LDS row pad in halves (136B rows)

typedef _Float16 f16;
typedef _Float16 f16x2 __attribute__((ext_vector_type(2)));
typedef _Float16 f16x4 __attribute__((ext_vector_type(4)));

#if __has_builtin(__builtin_amdgcn_fdot2)
__device__ inline float FDOT2(f16x2 a, f16x2 b, float c) {
    return __builtin_amdgcn_fdot2(a, b, c, false);
}
#else
__device__ inline float FDOT2(f16x2 a, f16x2 b, float c) {
    return c + (float)a.x * (float)b.x + (float)a.y * (float)b.y;
}
#endif

// ---------------- Stage A: holographic fusion -> e0h [N,64] f16 ----------------
__global__ void fuse_kernel(const float* __restrict__ aux,
                            const float* __restrict__ entity,
                            const float* __restrict__ type_emb,
                            const float* __restrict__ W_aux,
                            const float* __restrict__ b_aux,
                            f16* __restrict__ e0h)
{
    int n    = blockIdx.x * 4 + (threadIdx.x >> 6);
    int lane = threadIdx.x & 63;

    float a0 = log1pf(aux[n * 3 + 0]);
    float a1 = log1pf(aux[n * 3 + 1]);
    float a2 = log1pf(aux[n * 3 + 2]);
    float g  = a0 * W_aux[lane * 3 + 0] + a1 * W_aux[lane * 3 + 1]
             + a2 * W_aux[lane * 3 + 2] + b_aux[lane];
    g = 1.0f / (1.0f + expf(-g)) * 0.15f + 1.0f;

    float v  = entity[n * 64 + lane] * g;
    float ss = v * v;
    #pragma unroll
    for (int m = 32; m >= 1; m >>= 1) ss += __shfl_xor(ss, m);
    v = v / fmaxf(sqrtf(ss), 1e-12f);
    v += type_emb[(n >= ENT_OFFSET ? 1 : 0) * 64 + lane];

    e0h[n * 64 + lane] = (f16)v;
}

// ---------------- CSR build: bucketed two-level counting sort ----------------
__global__ void bucket_hist(const int* __restrict__ rows, int E, int* __restrict__ bcnt)
{
    __shared__ int lh[NBK];
    for (int b = threadIdx.x; b < NBK; b += blockDim.x) lh[b] = 0;
    __syncthreads();
    int i = blockIdx.x * blockDim.x + threadIdx.x;
    int s = gridDim.x * blockDim.x;
    for (; i < E; i += s) atomicAdd(&lh[rows[i] >> BSH], 1);
    __syncthreads();
    for (int b = threadIdx.x; b < NBK; b += blockDim.x)
        if (lh[b]) atomicAdd(&bcnt[b], lh[b]);
}

__global__ __launch_bounds__(1024) void bucket_scan(const int* __restrict__ bcnt,
                                                    int* __restrict__ bstart,
                                                    int* __restrict__ bfill,
                                                    int* __restrict__ rowptr, int E)
{
    __shared__ int lds[1024];
    int t = threadIdx.x;
    int v = (t < NBK) ? bcnt[t] : 0;
    lds[t] = v;
    __syncthreads();
    for (int off = 1; off < 1024; off <<= 1) {
        int u = (t >= off) ? lds[t - off] : 0;
        __syncthreads();
        lds[t] += u;
        __syncthreads();
    }
    if (t < NBK) { bstart[t + 1] = lds[t]; bfill[t] = 0; }
    if (t == 0)  { bstart[0] = 0; rowptr[NN] = E; }
}

__global__ __launch_bounds__(256) void bucket_scatter(
    const int* __restrict__ rows, const int* __restrict__ cols,
    const float* __restrict__ vals, int E,
    const int* __restrict__ bstart, int* __restrict__ bfill,
    uint2* __restrict__ cv)
{
    __shared__ int lhist[NBK];
    __shared__ int gpos[NBK];
    int tid   = threadIdx.x;
    int gbase = blockIdx.x * TILE_C;
    int n     = min(TILE_C, E - gbase);

    for (int b = tid; b < NBK; b += 256) lhist[b] = 0;
    __syncthreads();
    for (int i = tid; i < n; i += 256)
        atomicAdd(&lhist[rows[gbase + i] >> BSH], 1);
    __syncthreads();
    for (int b = tid; b < NBK; b += 256) {
        int c = lhist[b];
        if (c > 0) gpos[b] = bstart[b] + atomicAdd(&bfill[b], c);
        lhist[b] = 0;
    }
    __syncthreads();
    for (int i = tid; i < n; i += 256) {
        int r = rows[gbase + i];
        int b = r >> BSH;
        int ofs = atomicAdd(&lhist[b], 1);
        unsigned meta = (unsigned)cols[gbase + i] | ((unsigned)(r & 127) << 17);
        cv[gpos[b] + ofs] = make_uint2(meta, __float_as_uint(vals[gbase + i]));
    }
}

__global__ __launch_bounds__(256) void bucket_sort(
    const int* __restrict__ bstart, uint2* __restrict__ cv, int* __restrict__ rowptr)
{
    __shared__ uint2 raw[CAPD];
    __shared__ int hist[128], excl[128], fill[128];
    int b = blockIdx.x, tid = threadIdx.x;
    int base = bstart[b];
    int count = bstart[b + 1] - base;

    if (tid < 128) { hist[tid] = 0; fill[tid] = 0; }
    __syncthreads();
    for (int i = tid; i < count && i < CAPD; i += 256) {
        uint2 e = cv[base + i];
        raw[i] = e;
        atomicAdd(&hist[(e.x >> 17) & 127], 1);
    }
    __syncthreads();
    if (tid < 128) excl[tid] = hist[tid];
    __syncthreads();
    for (int off = 1; off < 128; off <<= 1) {
        int v = (tid < 128 && tid >= off) ? excl[tid - off] : 0;
        __syncthreads();
        if (tid < 128) excl[tid] += v;
        __syncthreads();
    }
    if (tid < 128) {
        int ex = excl[tid] - hist[tid];
        excl[tid] = ex;
        int g = (b << BSH) + tid;
        if (g < NN) rowptr[g] = base + ex;
    }
    __syncthreads();
    for (int i = tid; i < count && i < CAPD; i += 256) {
        uint2 e = raw[i];
        int lr = (e.x >> 17) & 127;
        int ofs = excl[lr] + atomicAdd(&fill[lr], 1);
        cv[base + ofs] = make_uint2(e.x & 0x1FFFF, e.y);
    }
}

// ---------------- SpMM (CSR): one wave per row, f16 gathers, f32 accum ----------------
__global__ __launch_bounds__(256) void spmm_csr_kernel(
    const int* __restrict__ rowptr, const uint2* __restrict__ cv,
    const f16* __restrict__ x, f16* __restrict__ side)
{
    int r = (blockIdx.x * blockDim.x + threadIdx.x) >> 6;
    if (r >= NN) return;
    int lane = threadIdx.x & 63;
    int s = rowptr[r], e = rowptr[r + 1];

    float acc = 0.0f;
    int i = s;
    for (; i + 4 <= e; i += 4) {
        uint2 e0 = cv[i],     e1 = cv[i + 1];
        uint2 e2 = cv[i + 2], e3 = cv[i + 3];
        float x0 = (float)x[(size_t)e0.x * 64 + lane];
        float x1 = (float)x[(size_t)e1.x * 64 + lane];
        float x2 = (float)x[(size_t)e2.x * 64 + lane];
        float x3 = (float)x[(size_t)e3.x * 64 + lane];
        acc += __uint_as_float(e0.y) * x0 + __uint_as_float(e1.y) * x1
             + __uint_as_float(e2.y) * x2 + __uint_as_float(e3.y) * x3;
    }
    for (; i < e; i++) {
        uint2 e0 = cv[i];
        acc += __uint_as_float(e0.y) * (float)x[(size_t)e0.x * 64 + lane];
    }
    side[r * 64 + lane] = (f16)acc;
}

// ---------------- Dense conv layer v3: f16 LDS + v_dot2_f32_f16 ----------------
template <int OUT, bool NORM>
__global__ __launch_bounds__(256) void layer_kernel(
    const f16* __restrict__ x,                 // [N,64] f16
    const f16* __restrict__ side,              // [N,64] f16
    const float* __restrict__ W1, const float* __restrict__ b1,
    const float* __restrict__ W2, const float* __restrict__ b2,
    f16* __restrict__ out,                     // [N,OUT] f16
    float* __restrict__ scale_out)
{
    constexpr int OPT = OUT / 8;
    __shared__ f16 W1h[OUT * HPAD];
    __shared__ f16 W2h[OUT * HPAD];
    __shared__ f16 s_sum[64 * HPAD];
    __shared__ f16 s_bi [64 * HPAD];

    int tid = threadIdx.x;
    int n0  = blockIdx.x * 64;

    for (int t = tid; t < OUT * 64; t += 256) {
        int r = t >> 6, c = t & 63;
        W1h[r * HPAD + c] = (f16)W1[t];
        W2h[r * HPAD + c] = (f16)W2[t];
    }
    // stage x+side / x*side as f16 (vectorized f16x4 global loads)
    for (int t = tid; t < 64 * 16; t += 256) {
        int n = t >> 4, q = t & 15;            // node, quad-of-4-dims
        int gn = n0 + n;
        f16x4 xe = {0,0,0,0}, sd = {0,0,0,0};
        if (gn < NN) {
            xe = *(const f16x4*)&x[(size_t)gn * 64 + q * 4];
            sd = *(const f16x4*)&side[(size_t)gn * 64 + q * 4];
        }
        f16x4 sm, bi;
        #pragma unroll
        for (int k = 0; k < 4; k++) {
            float xf = (float)xe[k], sf = (float)sd[k];
            sm[k] = (f16)(xf + sf);
            bi[k] = (f16)(xf * sf);
        }
        *(f16x4*)&s_sum[n * HPAD + q * 4] = sm;
        *(f16x4*)&s_bi [n * HPAD + q * 4] = bi;
    }
    __syncthreads();

    int og = tid & 7;
    int nb = tid >> 3;
    int nA = nb * 2, nB = nA + 1;

    float acc1[2][OPT], acc2[2][OPT];
    #pragma unroll
    for (int i = 0; i < OPT; i++) {
        int o = og + 8 * i;
        acc1[0][i] = b1[o]; acc1[1][i] = b1[o];
        acc2[0][i] = b2[o]; acc2[1][i] = b2[o];
    }

    #pragma unroll 4
    for (int d4 = 0; d4 < 16; d4++) {
        f16x4 sA = *(const f16x4*)&s_sum[nA * HPAD + d4 * 4];
        f16x4 bA = *(const f16x4*)&s_bi [nA * HPAD + d4 * 4];
        f16x4 sB = *(const f16x4*)&s_sum[nB * HPAD + d4 * 4];
        f16x4 bB = *(const f16x4*)&s_bi [nB * HPAD + d4 * 4];
        f16x2 sA0 = {sA[0], sA[1]}, sA1 = {sA[2], sA[3]};
        f16x2 bA0 = {bA[0], bA[1]}, bA1 = {bA[2], bA[3]};
        f16x2 sB0 = {sB[0], sB[1]}, sB1 = {sB[2], sB[3]};
        f16x2 bB0 = {bB[0], bB[1]}, bB1 = {bB[2], bB[3]};
        #pragma unroll
        for (int i = 0; i < OPT; i++) {
            int o = og + 8 * i;
            f16x4 w1 = *(const f16x4*)&W1h[o * HPAD + d4 * 4];
            f16x4 w2 = *(const f16x4*)&W2h[o * HPAD + d4 * 4];
            f16x2 w10 = {w1[0], w1[1]}, w11 = {w1[2], w1[3]};
            f16x2 w20 = {w2[0], w2[1]}, w21 = {w2[2], w2[3]};
            acc1[0][i] = FDOT2(sA1, w11, FDOT2(sA0, w10, acc1[0][i]));
            acc1[1][i] = FDOT2(sB1, w11, FDOT2(sB0, w10, acc1[1][i]));
            acc2[0][i] = FDOT2(bA1, w21, FDOT2(bA0, w20, acc2[0][i]));
            acc2[1][i] = FDOT2(bB1, w21, FDOT2(bB0, w20, acc2[1][i]));
        }
    }

    float eo[2][OPT];
    float ss0 = 0.0f, ss1 = 0.0f;
    #pragma unroll
    for (int i = 0; i < OPT; i++) {
        float a = acc1[0][i]; a = a > 0.0f ? a : 0.01f * a;
        float c = acc2[0][i]; c = c > 0.0f ? c : 0.01f * c;
        eo[0][i] = a + c; ss0 += eo[0][i] * eo[0][i];
        a = acc1[1][i]; a = a > 0.0f ? a : 0.01f * a;
        c = acc2[1][i]; c = c > 0.0f ? c : 0.01f * c;
        eo[1][i] = a + c; ss1 += eo[1][i] * eo[1][i];
    }
    #pragma unroll
    for (int m = 1; m <= 4; m <<= 1) {
        ss0 += __shfl_xor(ss0, m);
        ss1 += __shfl_xor(ss1, m);
    }
    float inv0 = 1.0f / fmaxf(sqrtf(ss0), 1e-12f);
    float inv1 = 1.0f / fmaxf(sqrtf(ss1), 1e-12f);

    int gnA = n0 + nA, gnB = n0 + nB;
    #pragma unroll
    for (int i = 0; i < OPT; i++) {
        int o = og + 8 * i;
        if (gnA < NN) out[(size_t)gnA * OUT + o] = (f16)(NORM ? eo[0][i] * inv0 : eo[0][i]);
        if (gnB < NN) out[(size_t)gnB * OUT + o] = (f16)(NORM ? eo[1][i] * inv1 : eo[1][i]);
    }
    if (!NORM && og == 0) {
        if (gnA < NN) scale_out[gnA] = inv0;
        if (gnB < NN) scale_out[gnB] = inv1;
    }
}

// ---------------- Score GEMM: 64x64 tile, 4x4 register blocking ----------------
__global__ __launch_bounds__(256) void score_kernel(
    const f16* __restrict__ e0, const f16* __restrict__ e1,
    const f16* __restrict__ e2, const float* __restrict__ scale1,
    const int* __restrict__ uids, const int* __restrict__ iids,
    float* __restrict__ out, int n_items)
{
    __shared__ float Us[64 * 36];
    __shared__ float Vs[64 * 36];
    int i0 = blockIdx.y * 64;
    int j0 = blockIdx.x * 64;
    int tid = threadIdx.x;
    int tx = tid & 15, ty = tid >> 4;

    float acc[4][4];
    #pragma unroll
    for (int a = 0; a < 4; a++)
        #pragma unroll
        for (int b = 0; b < 4; b++) acc[a][b] = 0.0f;

    for (int kc = 0; kc < 160; kc += 32) {
        __syncthreads();
        for (int t = tid; t < 64 * 32; t += 256) {
            int r = t >> 5, c = t & 31;
            int uid = uids[i0 + r];
            int iid = iids[j0 + r];
            float u, v;
            if (kc < 64) {
                u = (float)e0[(size_t)uid * 64 + kc + c];
                v = (float)e0[(size_t)iid * 64 + kc + c];
            } else if (kc < 128) {
                u = (float)e1[(size_t)uid * 64 + (kc - 64) + c] * scale1[uid];
                v = (float)e1[(size_t)iid * 64 + (kc - 64) + c] * scale1[iid];
            } else {
                u = (float)e2[(size_t)uid * 32 + (kc - 128) + c];
                v = (float)e2[(size_t)iid * 32 + (kc - 128) + c];
            }
            Us[r * 36 + c] = u;
            Vs[r * 36 + c] = v;
        }
        __syncthreads();
        #pragma unroll
        for (int k4 = 0; k4 < 8; k4++) {
            float4 u[4], v[4];
            #pragma unroll
            for (int a = 0; a < 4; a++) {
                u[a] = *(const float4*)&Us[(ty + 16 * a) * 36 + k4 * 4];
                v[a] = *(const float4*)&Vs[(tx + 16 * a) * 36 + k4 * 4];
            }
            #pragma unroll
            for (int a = 0; a < 4; a++)
                #pragma unroll
                for (int b = 0; b < 4; b++)
                    acc[a][b] += u[a].x * v[b].x + u[a].y * v[b].y
                               + u[a].z * v[b].z + u[a].w * v[b].w;
        }
    }
    #pragma unroll
    for (int a = 0; a < 4; a++) {
        int i = i0 + ty + 16 * a;
        #pragma unroll
        for (int b = 0; b < 4; b++) {
            int j = j0 + tx + 16 * b;
            out[(size_t)i * n_items + j] = acc[a][b];
        }
    }
}

extern "C" void kernel_launch(void* const* d_in, const int* in_sizes, int n_in,
                              void* d_out, int out_size, void* d_ws, size_t ws_size,
                              hipStream_t stream) {
    const int*   user_ids = (const int*)  d_in[0];
    const int*   item_ids = (const int*)  d_in[1];
    const float* aux      = (const float*)d_in[2];
    const int*   A_rows   = (const int*)  d_in[3];
    const int*   A_cols   = (const int*)  d_in[4];
    const float* A_vals   = (const float*)d_in[5];
    const float* entity   = (const float*)d_in[6];
    const float* type_emb = (const float*)d_in[7];
    const float* W_aux    = (const float*)d_in[8];
    const float* b_aux    = (const float*)d_in[9];
    const float* W1_0     = (const float*)d_in[10];
    const float* b1_0     = (const float*)d_in[11];
    const float* W2_0     = (const float*)d_in[12];
    const float* b2_0     = (const float*)d_in[13];
    const float* W1_1     = (const float*)d_in[14];
    const float* b1_1     = (const float*)d_in[15];
    const float* W2_1     = (const float*)d_in[16];
    const float* b2_1     = (const float*)d_in[17];

    int E       = in_sizes[3];
    int n_users = in_sizes[0];
    int n_items = in_sizes[1];

    char* ws = (char*)d_ws;
    size_t off = 0;
    f16*   e0     = (f16*)  (ws + off); off += (size_t)NN * 64 * 2;    // 12.8 MB
    f16*   e1     = (f16*)  (ws + off); off += (size_t)NN * 64 * 2;    // 12.8 MB
    f16*   e2     = (f16*)  (ws + off); off += (size_t)NN * 32 * 2;    //  6.4 MB
    f16*   side   = (f16*)  (ws + off); off += (size_t)NN * 64 * 2;    // 12.8 MB
    uint2* cv     = (uint2*)(ws + off); off += (size_t)E * 8;          // 12.8 MB
    float* scale1 = (float*)(ws + off); off += (size_t)NN * 4;
    int*   rowptr = (int*)  (ws + off); off += (size_t)(NN + 1) * 4;
    int*   bcnt   = (int*)  (ws + off); off += (size_t)NBK * 4;
    int*   bstart = (int*)  (ws + off); off += (size_t)(NBK + 1) * 4;
    int*   bfill  = (int*)  (ws + off); off += (size_t)NBK * 4;

    // ---- CSR build (bucketed two-level sort, reused by both layers) ----
    hipMemsetAsync(bcnt, 0, (size_t)NBK * 4, stream);
    bucket_hist<<<512, 256, 0, stream>>>(A_rows, E, bcnt);
    bucket_scan<<<1, 1024, 0, stream>>>(bcnt, bstart, bfill, rowptr, E);
    bucket_scatter<<<(E + TILE_C - 1) / TILE_C, 256, 0, stream>>>(
        A_rows, A_cols, A_vals, E, bstart, bfill, cv);
    bucket_sort<<<NBK, 256, 0, stream>>>(bstart, cv, rowptr);

    // ---- Stage A ----
    fuse_kernel<<<NN / 4, 256, 0, stream>>>(aux, entity, type_emb, W_aux, b_aux, e0);

    int lgrid = (NN + 63) / 64;
    int sgrid_rows = (NN + 3) / 4;

    // ---- Layer 0 ----
    spmm_csr_kernel<<<sgrid_rows, 256, 0, stream>>>(rowptr, cv, e0, side);
    layer_kernel<64, false><<<lgrid, 256, 0, stream>>>(e0, side,
                                                       W1_0, b1_0, W2_0, b2_0,
                                                       e1, scale1);

    // ---- Layer 1 (e1 unnormalized; reference feeds unnormalized forward) ----
    spmm_csr_kernel<<<sgrid_rows, 256, 0, stream>>>(rowptr, cv, e1, side);
    layer_kernel<32, true><<<lgrid, 256, 0, stream>>>(e1, side,
                                                      W1_1, b1_1, W2_1, b2_1,
                                                      e2, nullptr);

    // ---- Score ----
    dim3 sgrid(n_items / 64, n_users / 64);
    score_kernel<<<sgrid, 256, 0, stream>>>(e0, e1, e2, scale1, user_ids, item_ids,
                                            (float*)d_out, n_items);
}